// Round 1
// baseline (878.555 us; speedup 1.0000x reference)
//
#include <hip/hip_runtime.h>
#include <hip/hip_bf16.h>
#include <math.h>

#define B_ 128
#define T_ 512
#define H_ 1024
#define L_ 23
#define EMS 24  // padded emission row stride (floats)

// ---------------- Kernel 1: emissions = hs @ W + b ----------------
// One row (length 1024) per thread; 23 fp32 accumulators; K-ascending fmaf
// to stay numerically close to a canonical sequential-K sum.
__global__ __launch_bounds__(256) void emis_kernel(
    const float* __restrict__ hs, const float* __restrict__ W,
    const float* __restrict__ bias, float* __restrict__ em) {
  int row = blockIdx.x * blockDim.x + threadIdx.x;
  const float4* x4 = (const float4*)(hs + (size_t)row * H_);
  float acc[L_];
#pragma unroll
  for (int l = 0; l < L_; ++l) acc[l] = 0.f;
#pragma unroll 4
  for (int h4 = 0; h4 < H_ / 4; ++h4) {
    float4 v = x4[h4];
    const float* wr = W + (size_t)h4 * 4 * L_;  // wave-uniform -> s_load
#pragma unroll
    for (int l = 0; l < L_; ++l) acc[l] = fmaf(v.x, wr[l], acc[l]);
#pragma unroll
    for (int l = 0; l < L_; ++l) acc[l] = fmaf(v.y, wr[L_ + l], acc[l]);
#pragma unroll
    for (int l = 0; l < L_; ++l) acc[l] = fmaf(v.z, wr[2 * L_ + l], acc[l]);
#pragma unroll
    for (int l = 0; l < L_; ++l) acc[l] = fmaf(v.w, wr[3 * L_ + l], acc[l]);
  }
  float* o = em + (size_t)row * EMS;
#pragma unroll
  for (int l = 0; l < L_; ++l) o[l] = acc[l] + bias[l];
}

// single-wave LDS ordering (no cross-wave data here, so no s_barrier needed)
__device__ __forceinline__ void lds_fence() {
  asm volatile("s_waitcnt lgkmcnt(0)" ::: "memory");
}

// ---------------- Kernel 2: per-batch CRF (score+logZ) and Viterbi ----------
// Block = 1 batch, 128 threads = 2 waves.
// wave0: gold score + forward logsumexp (llh[b]).
// wave1: viterbi forward + backtrack + prediction stores.
__global__ __launch_bounds__(128) void crf_kernel(
    const float* __restrict__ em, const int* __restrict__ am,
    const int* __restrict__ labels, const float* __restrict__ startT,
    const float* __restrict__ endT, const float* __restrict__ trans,
    float* __restrict__ llh, float* __restrict__ out) {
  __shared__ float expTT[L_ * 25];          // expTT[j*25+i] = exp(T[i][j])
  __shared__ float Tt[L_ * 25];             // Tt[j*25+i]   = T[i][j]
  __shared__ unsigned char bp[(T_ - 1) * L_];
  __shared__ unsigned char tags[T_];

  int b = blockIdx.x;
  int tid = threadIdx.x;
  int wid = tid >> 6;
  int lane = tid & 63;
  const float* emb = em + (size_t)b * T_ * EMS;
  const int* amb = am + b * T_;
  const int* lab = labels + b * T_;

  if (wid == 0) {
    // ---- stage exp(transitions), transposed ----
    for (int idx = lane; idx < L_ * L_; idx += 64) {
      int i = idx / L_, j = idx % L_;
      expTT[j * 25 + i] = __expf(trans[idx]);
    }
    lds_fence();

    // ---- gold score (parallel over t) ----
    float sc = 0.f;
    int cnt = 0;
    for (int t = lane; t < T_; t += 64) {
      int mk = (amb[t] == 1);
      cnt += mk;
      int lt = lab[t];
      float emt = emb[t * EMS + lt];
      if (t == 0) sc += startT[lt] + emt;
      else if (mk) sc += trans[lab[t - 1] * L_ + lt] + emt;
    }
#pragma unroll
    for (int off = 32; off >= 1; off >>= 1) {
      sc += __shfl_xor(sc, off);
      cnt += __shfl_xor(cnt, off);
    }
    sc += endT[lab[cnt - 1]];

    // ---- forward algorithm (logZ); lane j holds alpha[j] ----
    float alpha = (lane < L_) ? startT[lane] + emb[lane] : -INFINITY;
    for (int t = 1; t < T_; ++t) {
      if (amb[t] == 1) {            // uniform branch
        float m = alpha;
#pragma unroll
        for (int off = 16; off >= 1; off >>= 1)
          m = fmaxf(m, __shfl_xor(m, off));   // max over lanes 0..31 (>=23 are -inf)
        float e = __expf(alpha - m);          // lanes 23..31 -> 0
        if (lane < L_) {
          float s = 0.f;
#pragma unroll
          for (int i = 0; i < L_; ++i)
            s = fmaf(__shfl(e, i), expTT[lane * 25 + i], s);
          alpha = m + __logf(s) + emb[t * EMS + lane];
        }
      }
    }
    float v = (lane < L_) ? alpha + endT[lane] : -INFINITY;
    float m2 = v;
#pragma unroll
    for (int off = 16; off >= 1; off >>= 1)
      m2 = fmaxf(m2, __shfl_xor(m2, off));
    float e2 = __expf(v - m2);                // lanes 23..31 -> 0
#pragma unroll
    for (int off = 16; off >= 1; off >>= 1)
      e2 += __shfl_xor(e2, off);
    if (lane == 0) llh[b] = sc - (m2 + __logf(e2));
  } else {
    // ---- stage transitions, transposed ----
    for (int idx = lane; idx < L_ * L_; idx += 64) {
      int i = idx / L_, j = idx % L_;
      Tt[j * 25 + i] = trans[idx];
    }
    lds_fence();

    // ---- viterbi forward; lane j holds score[j] ----
    float s = (lane < L_) ? startT[lane] + emb[lane] : -INFINITY;
    for (int t = 1; t < T_; ++t) {
      int bpi = lane;  // identity when masked
      if (amb[t] == 1) {
        float best = -INFINITY;
        int bi = 0;
        float sv = s;
#pragma unroll
        for (int i = 0; i < L_; ++i) {
          float v = __shfl(sv, i) + Tt[lane * 25 + i];
          if (v > best) { best = v; bi = i; }   // strict > == first-index argmax
        }
        if (lane < L_) {
          s = best + emb[t * EMS + lane];
          bpi = bi;
        }
      }
      if (lane < L_) bp[(t - 1) * L_ + lane] = (unsigned char)bpi;
    }
    // final tag = first-index argmax of s + endT
    float v = (lane < L_) ? s + endT[lane] : -INFINITY;
    float m = v;
#pragma unroll
    for (int off = 16; off >= 1; off >>= 1)
      m = fmaxf(m, __shfl_xor(m, off));
    int cand = (v == m && lane < L_) ? lane : 64;
#pragma unroll
    for (int off = 16; off >= 1; off >>= 1)
      cand = min(cand, __shfl_xor(cand, off));
    lds_fence();   // bp writes visible
    if (lane == 0) {
      int cur = cand;
      tags[T_ - 1] = (unsigned char)cur;
      for (int t = T_ - 2; t >= 0; --t) {
        cur = bp[t * L_ + cur];
        tags[t] = (unsigned char)cur;
      }
    }
    lds_fence();
    for (int t = lane; t < T_; t += 64) {
      out[1 + b * T_ + t] = (amb[t] == 1) ? (float)tags[t] : 0.0f;
    }
  }
}

// ---------------- Kernel 3: loss = -mean(llh) ----------------
__global__ void finalize_kernel(const float* __restrict__ llh,
                                float* __restrict__ out) {
  int lane = threadIdx.x;
  float v = llh[lane] + llh[lane + 64];
#pragma unroll
  for (int off = 32; off >= 1; off >>= 1) v += __shfl_xor(v, off);
  if (lane == 0) out[0] = -v * (1.0f / (float)B_);
}

extern "C" void kernel_launch(void* const* d_in, const int* in_sizes, int n_in,
                              void* d_out, int out_size, void* d_ws, size_t ws_size,
                              hipStream_t stream) {
  const float* hs     = (const float*)d_in[0];
  const int*   am     = (const int*)d_in[1];
  const int*   labels = (const int*)d_in[2];
  const float* W      = (const float*)d_in[3];
  const float* bias   = (const float*)d_in[4];
  const float* startT = (const float*)d_in[5];
  const float* endT   = (const float*)d_in[6];
  const float* trans  = (const float*)d_in[7];
  float* out = (float*)d_out;

  float* em  = (float*)d_ws;                      // 65536 * 24 floats = 6.29 MB
  float* llh = em + (size_t)B_ * T_ * EMS;        // 128 floats

  emis_kernel<<<(B_ * T_) / 256, 256, 0, stream>>>(hs, W, bias, em);
  crf_kernel<<<B_, 128, 0, stream>>>(em, am, labels, startT, endT, trans, llh, out);
  finalize_kernel<<<1, 64, 0, stream>>>(llh, out);
}

// Round 2
// 749.211 us; speedup vs baseline: 1.1726x; 1.1726x over previous
//
#include <hip/hip_runtime.h>
#include <hip/hip_bf16.h>
#include <math.h>

#define B_ 128
#define T_ 512
#define H_ 1024
#define L_ 23
#define EMS 24      // padded emission row stride (floats)
#define NINF (-1.0f/0.0f)

__device__ __forceinline__ float rdl(float v, int l) {
  return __int_as_float(__builtin_amdgcn_readlane(__float_as_int(v), l));
}
__device__ __forceinline__ float rdfl(float v) {
  return __int_as_float(__builtin_amdgcn_readfirstlane(__float_as_int(v)));
}

// ---------------- Kernel 1: emissions = hs @ W + b ----------------
// 1024 blocks x 256 thr. Block owns 64 rows. K-chunks of 64 staged through
// LDS (coalesced global loads, transposed consume). Thread (r,q) = row r,
// k-quarter q (wave-uniform q -> W via s_load). 4-way combine in LDS.
#define EK 64
#define ES 67       // LDS row stride (odd -> conflict-free b32 reads)
__global__ __launch_bounds__(256) void emis_kernel(
    const float* __restrict__ hs, const float* __restrict__ W,
    const float* __restrict__ bias, float* __restrict__ em) {
  __shared__ float tile[2][64 * ES];
  const int tid = threadIdx.x;
  const int rowbase = blockIdx.x * 64;
  const int r = tid & 63;       // row within block
  const int q = tid >> 6;       // k-quarter (== wave id)
  const int lr = tid >> 4;      // 0..15 staging row group
  const int lc = tid & 15;      // 0..15 staging k group
  const float* gsrc = hs + (size_t)(rowbase + lr) * H_ + lc * 4;

  float4 st[4];
#define LOADC(c)                                                        \
  { _Pragma("unroll") for (int m = 0; m < 4; ++m)                       \
      st[m] = *(const float4*)(gsrc + (size_t)(16 * m) * H_ + (c)*EK); }
#define WRITEC(buf)                                                     \
  { _Pragma("unroll") for (int m = 0; m < 4; ++m) {                     \
      float* p = &tile[buf][(lr + 16 * m) * ES + lc * 4];               \
      p[0] = st[m].x; p[1] = st[m].y; p[2] = st[m].z; p[3] = st[m].w; } }

  float acc[L_];
#pragma unroll
  for (int l = 0; l < L_; ++l) acc[l] = 0.f;

  LOADC(0); WRITEC(0); LOADC(1);
  __syncthreads();

  for (int c = 0; c < 16; ++c) {
    const float* tp = &tile[c & 1][r * ES + q * 16];
    const float* wk = W + (size_t)(c * EK + q * 16) * L_;
#pragma unroll
    for (int kk = 0; kk < 16; ++kk) {
      float x = tp[kk];
      const float* wr = wk + kk * L_;   // wave-uniform -> s_load
#pragma unroll
      for (int l = 0; l < L_; ++l) acc[l] = fmaf(x, wr[l], acc[l]);
    }
    if (c < 15) {
      WRITEC((c + 1) & 1);
      if (c < 14) LOADC(c + 2);
      __syncthreads();
    }
  }

  // 4-way combine via LDS (reuse tile)
  __syncthreads();
  float* comb = (float*)tile;
  if (q > 0) {
    float* p = comb + ((q - 1) * 64 + r) * L_;
#pragma unroll
    for (int l = 0; l < L_; ++l) p[l] = acc[l];
  }
  __syncthreads();
  if (q == 0) {
#pragma unroll
    for (int l = 0; l < L_; ++l)
      acc[l] = acc[l] + comb[(0 * 64 + r) * L_ + l] + comb[(1 * 64 + r) * L_ + l]
             + comb[(2 * 64 + r) * L_ + l] + bias[l];
    float4* op = (float4*)(em + (size_t)(rowbase + r) * EMS);
    op[0] = make_float4(acc[0], acc[1], acc[2], acc[3]);
    op[1] = make_float4(acc[4], acc[5], acc[6], acc[7]);
    op[2] = make_float4(acc[8], acc[9], acc[10], acc[11]);
    op[3] = make_float4(acc[12], acc[13], acc[14], acc[15]);
    op[4] = make_float4(acc[16], acc[17], acc[18], acc[19]);
    op[5] = make_float4(acc[20], acc[21], acc[22], 0.0f);
  }
}

// ---------------- Kernel 2: CRF fwd/logZ (role 0) + Viterbi (role 1) -------
// Grid 256: block = (batch, role). 2 waves: wave0 compute, wave1 stage
// emissions (64-row chunks, double-buffered) + gold score (role 0).
__global__ __launch_bounds__(128) void crf_kernel(
    const float* __restrict__ em, const int* __restrict__ am,
    const int* __restrict__ labels, const float* __restrict__ startT,
    const float* __restrict__ endT, const float* __restrict__ trans,
    float* __restrict__ llh, float* __restrict__ out) {
  __shared__ float emb_lds[2][64 * EMS];
  __shared__ int bp_lds[(T_ - 1) * L_];
  __shared__ int tags_sh[T_];
  __shared__ float score_sh;

  const int role = blockIdx.x & 1;
  const int b = blockIdx.x >> 1;
  const int wid = threadIdx.x >> 6;
  const int lane = threadIdx.x & 63;
  const int eml = (lane < L_) ? lane : 0;
  const float* emb = em + (size_t)b * T_ * EMS;
  const int* amb = am + b * T_;
  const int* lab = labels + b * T_;

  // per-lane persistent state (wave0)
  float state = NINF;            // alpha (role0) / viterbi score (role1)
  float colT[L_];                // exp(T[i][lane]) or T[i][lane]
  float st_r = 0.f, end_r = 0.f;
  if (wid == 0) {
    st_r = startT[eml];
    end_r = endT[eml];
#pragma unroll
    for (int i = 0; i < L_; ++i) {
      float tv = trans[i * L_ + eml];
      colT[i] = (role == 0) ? __expf(tv) : tv;
    }
  }

  int av = amb[lane];            // mask values for chunk 0 (all lanes)

  for (int c = 0; c < 8; ++c) {
    if (wid == 1) {
      const float* src = emb + c * (64 * EMS);
      float4 v[6];
#pragma unroll
      for (int i = 0; i < 6; ++i)
        v[i] = *(const float4*)(src + i * 256 + lane * 4);
#pragma unroll
      for (int i = 0; i < 6; ++i)
        *(float4*)&emb_lds[c & 1][i * 256 + lane * 4] = v[i];
    }
    __syncthreads();
    if (wid == 0) {
      int av_nxt = (c < 7) ? amb[(c + 1) * 64 + lane] : 0;
      unsigned long long mkb = __ballot(av == 1);
      const float* eb = &emb_lds[c & 1][0];
      int s0 = 0;
      if (c == 0) {
        state = (lane < L_) ? st_r + eb[lane] : NINF;
        s0 = 1;
      }
      if (role == 0) {
        // ---- forward (logsumexp) ----
#pragma unroll 4
        for (int s = s0; s < 64; ++s) {
          float ee = eb[s * EMS + eml];
          bool mk = (mkb >> s) & 1ull;
          float m0 = rdfl(state);
          float ex = __expf(state - m0);   // lanes >= L: exp(-inf)=0
          float p0 = 0.f, p1 = 0.f, p2 = 0.f, p3 = 0.f;
#pragma unroll
          for (int i = 0; i < 20; i += 4) {
            p0 = fmaf(rdl(ex, i + 0), colT[i + 0], p0);
            p1 = fmaf(rdl(ex, i + 1), colT[i + 1], p1);
            p2 = fmaf(rdl(ex, i + 2), colT[i + 2], p2);
            p3 = fmaf(rdl(ex, i + 3), colT[i + 3], p3);
          }
          p0 = fmaf(rdl(ex, 20), colT[20], p0);
          p1 = fmaf(rdl(ex, 21), colT[21], p1);
          p2 = fmaf(rdl(ex, 22), colT[22], p2);
          float sum = (p0 + p1) + (p2 + p3);
          float nxt = m0 + __logf(sum) + ee;
          state = (mk && lane < L_) ? nxt : state;
        }
      } else {
        // ---- viterbi forward ----
#pragma unroll 2
        for (int s = s0; s < 64; ++s) {
          int t = c * 64 + s;
          float ee = eb[s * EMS + eml];
          bool mk = (mkb >> s) & 1ull;
          float ci[L_];
#pragma unroll
          for (int i = 0; i < L_; ++i) ci[i] = rdl(state, i) + colT[i];
          // pairwise max tree
          float m1[12];
#pragma unroll
          for (int i = 0; i < 11; ++i) m1[i] = fmaxf(ci[2 * i], ci[2 * i + 1]);
          m1[11] = ci[22];
          float m2[6];
#pragma unroll
          for (int i = 0; i < 6; ++i) m2[i] = fmaxf(m1[2 * i], m1[2 * i + 1]);
          float m3a = fmaxf(m2[0], m2[1]), m3b = fmaxf(m2[2], m2[3]),
                m3c = fmaxf(m2[4], m2[5]);
          float best = fmaxf(fmaxf(m3a, m3b), m3c);
          int bi = 22;
#pragma unroll
          for (int i = 21; i >= 0; --i) bi = (ci[i] == best) ? i : bi;
          float snew = best + ee;
          int bpv = mk ? bi : lane;
          state = (mk && lane < L_) ? snew : state;
          if (lane < L_) bp_lds[(t - 1) * L_ + lane] = bpv;
        }
      }
      av = av_nxt;
    }
  }

  // gold score on wave1 (role 0) — overlaps wave0's last chunk
  if (wid == 1 && role == 0) {
    float sc = 0.f;
    int cnt = 0;
#pragma unroll
    for (int it = 0; it < 8; ++it) {
      int t = it * 64 + lane;
      int mk = (amb[t] == 1);
      cnt += mk;
      int lt = lab[t];
      float emt = emb[t * EMS + lt];
      if (t == 0) sc += startT[lt] + emt;
      else if (mk) sc += trans[lab[t - 1] * L_ + lt] + emt;
    }
#pragma unroll
    for (int off = 32; off >= 1; off >>= 1) {
      sc += __shfl_xor(sc, off);
      cnt += __shfl_xor(cnt, off);
    }
    sc += endT[lab[cnt - 1]];
    if (lane == 0) score_sh = sc;
  }
  __syncthreads();

  if (wid == 0) {
    if (role == 0) {
      // logZ (true max for final reduce)
      float v = (lane < L_) ? state + end_r : NINF;
      float mx = v;
#pragma unroll
      for (int off = 32; off >= 1; off >>= 1) mx = fmaxf(mx, __shfl_xor(mx, off));
      float e2 = __expf(v - mx);
#pragma unroll
      for (int off = 32; off >= 1; off >>= 1) e2 += __shfl_xor(e2, off);
      if (lane == 0) llh[b] = score_sh - (mx + __logf(e2));
    } else {
      // final argmax (first-index)
      float v = (lane < L_) ? state + end_r : NINF;
      float mx = v;
#pragma unroll
      for (int off = 32; off >= 1; off >>= 1) mx = fmaxf(mx, __shfl_xor(mx, off));
      int cand = (v == mx && lane < L_) ? lane : 64;
#pragma unroll
      for (int off = 32; off >= 1; off >>= 1) cand = min(cand, __shfl_xor(cand, off));
      int cur = __builtin_amdgcn_readfirstlane(cand);
      if (lane == 0) tags_sh[T_ - 1] = cur;
      // backtrack: all 23 lanes load the bp row, scalar readlane chain
#pragma unroll 8
      for (int t = T_ - 2; t >= 0; --t) {
        int row = bp_lds[t * L_ + eml];
        cur = __builtin_amdgcn_readlane(row, cur);
        if (lane == 0) tags_sh[t] = cur;
      }
      // coalesced prediction stores
      for (int t = lane; t < T_; t += 64) {
        float o = (amb[t] == 1) ? (float)tags_sh[t] : 0.0f;
        out[1 + b * T_ + t] = o;
      }
    }
  }
}

// ---------------- Kernel 3: loss = -mean(llh) ----------------
__global__ void finalize_kernel(const float* __restrict__ llh,
                                float* __restrict__ out) {
  int lane = threadIdx.x;
  float v = llh[lane] + llh[lane + 64];
#pragma unroll
  for (int off = 32; off >= 1; off >>= 1) v += __shfl_xor(v, off);
  if (lane == 0) out[0] = -v * (1.0f / (float)B_);
}

extern "C" void kernel_launch(void* const* d_in, const int* in_sizes, int n_in,
                              void* d_out, int out_size, void* d_ws, size_t ws_size,
                              hipStream_t stream) {
  const float* hs     = (const float*)d_in[0];
  const int*   am     = (const int*)d_in[1];
  const int*   labels = (const int*)d_in[2];
  const float* W      = (const float*)d_in[3];
  const float* bias   = (const float*)d_in[4];
  const float* startT = (const float*)d_in[5];
  const float* endT   = (const float*)d_in[6];
  const float* trans  = (const float*)d_in[7];
  float* out = (float*)d_out;

  float* em  = (float*)d_ws;                      // 65536 * 24 floats = 6.29 MB
  float* llh = em + (size_t)B_ * T_ * EMS;        // 128 floats

  emis_kernel<<<B_ * T_ / 64, 256, 0, stream>>>(hs, W, bias, em);
  crf_kernel<<<2 * B_, 128, 0, stream>>>(em, am, labels, startT, endT, trans, llh, out);
  finalize_kernel<<<1, 64, 0, stream>>>(llh, out);
}